// Round 2
// baseline (382.676 us; speedup 1.0000x reference)
//
#include <hip/hip_runtime.h>

// AdaptiveSpectrumLayer: B=128, H=T=512, F=16, HID=64, NF=257
// Pipeline: k_wgt (W_gate->bf16 transposed) ; k_csd (pair-mean CSD == autocorr of
// feature-sum) ; k_fft (rfft DFT + csd) ; k_new (proj->mag/phase->new_fft) ;
// k_gemm (gate GEMM, bf16 MFMA, A recomputed from fftc, split-K=4) ; k_wred
// (reduce+SiLU+sigmoid->w) ; k_recon (blend + irfft + residual + LayerNorm).

#define NF_ 257
#define KDIM 16448   // NF_*64
#define NPAD 320

typedef __attribute__((ext_vector_type(8))) short short8;
typedef __attribute__((ext_vector_type(4))) float floatx4;

__device__ __forceinline__ unsigned short f2bf(float x) {
  union { float f; unsigned int u; } v; v.f = x;
  unsigned int r = (v.u + 0x7FFFu + ((v.u >> 16) & 1u)) >> 16;
  return (unsigned short)r;
}

// ---------- K0: W_gate (16448 x 257 f32) -> wgt bf16, transposed+padded (320 x 16448)
__global__ __launch_bounds__(256) void k_wgt(const float* __restrict__ Wg,
                                             unsigned short* __restrict__ wgt) {
  __shared__ float tile[32][33];
  const int tid = threadIdx.x;
  const int k0 = blockIdx.x * 32, n0 = blockIdx.y * 32;
  const int c = tid & 31, r = tid >> 5;
#pragma unroll
  for (int j = 0; j < 4; ++j) {
    int rr = r + j * 8;
    int n = n0 + c;
    tile[rr][c] = (n < NF_) ? Wg[(k0 + rr) * NF_ + n] : 0.f;
  }
  __syncthreads();
#pragma unroll
  for (int j = 0; j < 4; ++j) {
    int nn = r + j * 8;
    wgt[(n0 + nn) * KDIM + k0 + c] = f2bf(tile[c][nn]);
  }
}

// ---------- K1: csd[b][k] = (1/(256*sqrt(512))) * DFT_t( autocorr(s)[t-255] )
__global__ __launch_bounds__(256) void k_csd(const float* __restrict__ x,
                                             float* __restrict__ csd) {
  __shared__ float sl[512];
  __shared__ float ol[512];
  __shared__ float2 tw[512];
  const int tid = threadIdx.x, bb = blockIdx.x;
  for (int t = tid; t < 512; t += 256) {
    const float4* xp = (const float4*)(x + (bb * 512 + t) * 16);
    float4 a = xp[0], c = xp[1], d = xp[2], e = xp[3];
    sl[t] = a.x + a.y + a.z + a.w + c.x + c.y + c.z + c.w +
            d.x + d.y + d.z + d.w + e.x + e.y + e.z + e.w;
    float sv, cv; __sincosf((float)t * 0.01227184630f, &sv, &cv);  // 2*pi/512
    tw[t] = make_float2(cv, sv);
  }
  __syncthreads();
  for (int t = tid; t < 512; t += 256) {
    int l = t - 255;
    int lo = l < 0 ? -l : 0;
    int hi = l > 0 ? 511 - l : 511;
    float a = 0.f;
    for (int tau = lo; tau <= hi; ++tau) a += sl[tau] * sl[tau + l];
    ol[t] = a;
  }
  __syncthreads();
  const float S1 = 0.04419417382f / 256.f;
  for (int k = tid; k < NF_; k += 256) {
    float re = 0.f, im = 0.f; int id = 0;
    for (int t = 0; t < 512; ++t) {
      float ov = ol[t];
      float2 tv = tw[id];
      re = fmaf(ov, tv.x, re);
      im = fmaf(-ov, tv.y, im);
      id = (id + k) & 511;
    }
    *(float2*)(csd + (bb * NF_ + k) * 2) = make_float2(re * S1, im * S1);
  }
}

// ---------- K2: fftc[b][k][f] = ortho-rfft(x)[k,f] + csd[b][k]
__global__ __launch_bounds__(256) void k_fft(const float* __restrict__ x,
                                             const float* __restrict__ csd,
                                             float* __restrict__ fftc) {
  __shared__ float xs[4096];      // [t][8] for this f-half
  __shared__ float2 tw[512];
  const int tid = threadIdx.x;
  const int fh = blockIdx.x, bb = blockIdx.y;
  for (int j = tid; j < 512; j += 256) {
    float sv, cv; __sincosf((float)j * 0.01227184630f, &sv, &cv);
    tw[j] = make_float2(cv, sv);
  }
#pragma unroll
  for (int j = 0; j < 4; ++j) {
    int l = (tid + 256 * j) * 4;
    int t = l >> 3, fo = l & 7;
    *(float4*)(&xs[l]) = *(const float4*)(x + bb * 8192 + t * 16 + fh * 8 + fo);
  }
  __syncthreads();
  const int f = tid & 7, kk = tid >> 3;
  float re[8], im[8]; int id[8];
#pragma unroll
  for (int j = 0; j < 8; ++j) { re[j] = 0.f; im[j] = 0.f; id[j] = 0; }
  for (int t = 0; t < 512; ++t) {
    float xv = xs[t * 8 + f];
#pragma unroll
    for (int j = 0; j < 8; ++j) {
      float2 tv = tw[id[j]];
      re[j] = fmaf(xv, tv.x, re[j]);
      im[j] = fmaf(-xv, tv.y, im[j]);
      id[j] = (id[j] + kk + 32 * j) & 511;
    }
  }
  const float S = 0.04419417382f;  // 1/sqrt(512)
#pragma unroll
  for (int j = 0; j < 8; ++j) {
    int k = kk + 32 * j;
    float2 cz = *(const float2*)(csd + (bb * NF_ + k) * 2);
    *(float2*)(fftc + ((bb * NF_ + k) * 16 + fh * 8 + f) * 2) =
        make_float2(re[j] * S + cz.x, im[j] * S + cz.y);
  }
  if (kk == 0) {  // k = 256 tail
    float re9 = 0.f, im9 = 0.f; int id9 = 0;
    for (int t = 0; t < 512; ++t) {
      float xv = xs[t * 8 + f];
      float2 tv = tw[id9];
      re9 = fmaf(xv, tv.x, re9);
      im9 = fmaf(-xv, tv.y, im9);
      id9 = (id9 + 256) & 511;
    }
    float2 cz = *(const float2*)(csd + (bb * NF_ + 256) * 2);
    *(float2*)(fftc + ((bb * NF_ + 256) * 16 + fh * 8 + f) * 2) =
        make_float2(re9 * S + cz.x, im9 * S + cz.y);
  }
}

// ---------- K3: new_fft[b][n][f] from recomputed proj + per-freq complexifier
__global__ __launch_bounds__(256) void k_new(const float* __restrict__ fftc,
                                             const float* __restrict__ W_proj,
                                             const float* __restrict__ b_proj,
                                             const float* __restrict__ mag_w,
                                             const float* __restrict__ mag_b,
                                             const float* __restrict__ phase_w,
                                             const float* __restrict__ phase_b,
                                             float* __restrict__ nf) {
  __shared__ float wp[256], bp[64];
  const int tid = threadIdx.x;
  wp[tid] = W_proj[tid];
  if (tid < 64) bp[tid] = b_proj[tid];
  __syncthreads();
  const int idx = blockIdx.x * 256 + tid;  // < 128*257*16
  const int bn = idx >> 4;
  const int n = bn % NF_;
  float2 z = *(const float2*)(fftc + idx * 2);
  float d = z.x * z.x + z.y * z.y;
  float ir = d > 0.f ? rsqrtf(d) : 0.f;
  float mag = d * ir;
  float sn = z.y * ir;
  float cs = d > 0.f ? z.x * ir : 1.f;
  float fr = (float)n * 0.1953125f;  // 100/512
  float am = 0.f, ap = 0.f;
#pragma unroll 8
  for (int h = 0; h < 64; ++h) {
    float p = fmaf(mag, wp[h], fmaf(sn, wp[64 + h], fmaf(cs, wp[128 + h],
              fmaf(fr, wp[192 + h], bp[h]))));
    p = fmaxf(p, 0.f);
    am = fmaf(p, mag_w[n * 64 + h], am);
    ap = fmaf(p, phase_w[n * 64 + h], ap);
  }
  float m = fmaxf(am + mag_b[n], 0.f);
  float ph = 6.28318530718f / (1.f + __expf(-(ap + phase_b[n])));
  float sp, cp; __sincosf(ph, &sp, &cp);
  *(float2*)(nf + idx * 2) = make_float2(m * cp, m * sp);
}

// ---------- K4: gate GEMM partials. C(2048 x 320) = A(2048 x 16448) * B,
// A = proj recomputed from fftc (bf16), B = wgt bf16 [n][k]. split-K = 4.
__global__ __launch_bounds__(256) void k_gemm(const float* __restrict__ fftc,
                                              const float* __restrict__ W_proj,
                                              const float* __restrict__ b_proj,
                                              const unsigned short* __restrict__ wgt,
                                              float* __restrict__ gpart) {
  __shared__ __align__(16) unsigned short As[128 * 72];
  __shared__ __align__(16) unsigned short Bs[64 * 72];
  const int tid = threadIdx.x;
  const int mt = blockIdx.x, nt = blockIdx.y, sp = blockIdx.z;
  const int i0 = (NF_ * sp) >> 2, i1 = (NF_ * (sp + 1)) >> 2;

  // staging roles: thread stages rows {arow, arow+64}, h-chunk hc*16..+16
  const int arow = tid >> 2;
  const int hc = tid & 3;
  float w0[16], w1[16], w2[16], w3[16], bpv[16];
#pragma unroll
  for (int j = 0; j < 16; ++j) {
    int h = hc * 16 + j;
    w0[j] = W_proj[h];       w1[j] = W_proj[64 + h];
    w2[j] = W_proj[128 + h]; w3[j] = W_proj[192 + h];
    bpv[j] = b_proj[h];
  }
  const int gm1 = mt * 128 + arow, gm2 = gm1 + 64;
  const int bb1 = gm1 >> 4, ff1 = gm1 & 15;
  const int bb2 = gm2 >> 4, ff2 = gm2 & 15;
  const unsigned short* wrow = wgt + (nt * 64 + (tid >> 2)) * KDIM + (tid & 3) * 16;
  const int bcol = (tid & 3) * 16;

  const int lane = tid & 63, wave = tid >> 6;
  const int wm = wave & 1, wn = wave >> 1;
  const int l15 = lane & 15, quad = lane >> 4;

  floatx4 zero4 = {0.f, 0.f, 0.f, 0.f};
  floatx4 acc[4][2];
#pragma unroll
  for (int a = 0; a < 4; ++a)
#pragma unroll
    for (int c = 0; c < 2; ++c) acc[a][c] = zero4;

  for (int i = i0; i < i1; ++i) {
    // B chunk: this thread covers 16 shorts = 2 x uint4 of its row's 64-short slice
    uint4 bv0 = *(const uint4*)(wrow + i * 64);
    uint4 bv1 = *(const uint4*)(wrow + i * 64 + 8);
    float2 z1 = *(const float2*)(fftc + ((bb1 * NF_ + i) * 16 + ff1) * 2);
    float2 z2 = *(const float2*)(fftc + ((bb2 * NF_ + i) * 16 + ff2) * 2);
    float fr = (float)i * 0.1953125f;
    float d1 = z1.x * z1.x + z1.y * z1.y;
    float ir1 = d1 > 0.f ? rsqrtf(d1) : 0.f;
    float mag1 = d1 * ir1, sn1 = z1.y * ir1, cs1 = d1 > 0.f ? z1.x * ir1 : 1.f;
    float d2 = z2.x * z2.x + z2.y * z2.y;
    float ir2 = d2 > 0.f ? rsqrtf(d2) : 0.f;
    float mag2 = d2 * ir2, sn2 = z2.y * ir2, cs2 = d2 > 0.f ? z2.x * ir2 : 1.f;
    unsigned int pk1[8], pk2[8];
#pragma unroll
    for (int jj = 0; jj < 8; ++jj) {
      float p0 = fmaf(mag1, w0[2 * jj], fmaf(sn1, w1[2 * jj],
                 fmaf(cs1, w2[2 * jj], fmaf(fr, w3[2 * jj], bpv[2 * jj]))));
      float p1 = fmaf(mag1, w0[2 * jj + 1], fmaf(sn1, w1[2 * jj + 1],
                 fmaf(cs1, w2[2 * jj + 1], fmaf(fr, w3[2 * jj + 1], bpv[2 * jj + 1]))));
      float q0 = fmaf(mag2, w0[2 * jj], fmaf(sn2, w1[2 * jj],
                 fmaf(cs2, w2[2 * jj], fmaf(fr, w3[2 * jj], bpv[2 * jj]))));
      float q1 = fmaf(mag2, w0[2 * jj + 1], fmaf(sn2, w1[2 * jj + 1],
                 fmaf(cs2, w2[2 * jj + 1], fmaf(fr, w3[2 * jj + 1], bpv[2 * jj + 1]))));
      p0 = fmaxf(p0, 0.f); p1 = fmaxf(p1, 0.f);
      q0 = fmaxf(q0, 0.f); q1 = fmaxf(q1, 0.f);
      pk1[jj] = (unsigned int)f2bf(p0) | ((unsigned int)f2bf(p1) << 16);
      pk2[jj] = (unsigned int)f2bf(q0) | ((unsigned int)f2bf(q1) << 16);
    }
    __syncthreads();  // previous iteration's fragment reads complete
    *(uint4*)(&Bs[(tid >> 2) * 72 + bcol]) = bv0;
    *(uint4*)(&Bs[(tid >> 2) * 72 + bcol + 8]) = bv1;
    *(uint4*)(&As[arow * 72 + hc * 16]) = make_uint4(pk1[0], pk1[1], pk1[2], pk1[3]);
    *(uint4*)(&As[arow * 72 + hc * 16 + 8]) = make_uint4(pk1[4], pk1[5], pk1[6], pk1[7]);
    *(uint4*)(&As[(arow + 64) * 72 + hc * 16]) = make_uint4(pk2[0], pk2[1], pk2[2], pk2[3]);
    *(uint4*)(&As[(arow + 64) * 72 + hc * 16 + 8]) = make_uint4(pk2[4], pk2[5], pk2[6], pk2[7]);
    __syncthreads();
#pragma unroll
    for (int kh = 0; kh < 64; kh += 32) {
      short8 af[4], bf[2];
#pragma unroll
      for (int mi = 0; mi < 4; ++mi)
        af[mi] = *(const short8*)(&As[(wm * 64 + mi * 16 + l15) * 72 + kh + quad * 8]);
#pragma unroll
      for (int ni = 0; ni < 2; ++ni)
        bf[ni] = *(const short8*)(&Bs[(wn * 32 + ni * 16 + l15) * 72 + kh + quad * 8]);
#pragma unroll
      for (int mi = 0; mi < 4; ++mi)
#pragma unroll
        for (int ni = 0; ni < 2; ++ni)
          acc[mi][ni] = __builtin_amdgcn_mfma_f32_16x16x32_bf16(af[mi], bf[ni],
                                                                acc[mi][ni], 0, 0, 0);
    }
  }
  float* gp = gpart + sp * (2048 * NPAD);
#pragma unroll
  for (int mi = 0; mi < 4; ++mi)
#pragma unroll
    for (int ni = 0; ni < 2; ++ni)
#pragma unroll
      for (int r = 0; r < 4; ++r) {
        int row = mt * 128 + wm * 64 + mi * 16 + quad * 4 + r;
        int col = nt * 64 + wn * 32 + ni * 16 + l15;
        gp[row * NPAD + col] = acc[mi][ni][r];
      }
}

// ---------- K4r: sum split-K partials + bias -> SiLU -> sigmoid -> w
__global__ __launch_bounds__(256) void k_wred(const float* __restrict__ gpart,
                                              const float* __restrict__ b_gate,
                                              float* __restrict__ wbuf) {
  const int m = blockIdx.x;
  for (int n = threadIdx.x; n < NF_; n += 256) {
    float g = b_gate[n];
#pragma unroll
    for (int s2 = 0; s2 < 4; ++s2) g += gpart[s2 * (2048 * NPAD) + m * NPAD + n];
    float sg = 1.f / (1.f + __expf(-g));
    float gs = g * sg;
    wbuf[m * NF_ + n] = 1.f / (1.f + __expf(-gs));
  }
}

// ---------- K5: blend + ortho-irfft + residual + LayerNorm(F)
__global__ __launch_bounds__(256) void k_recon(const float* __restrict__ fftc,
                                               const float* __restrict__ nf,
                                               const float* __restrict__ wbuf,
                                               const float* __restrict__ x,
                                               const float* __restrict__ ln_g,
                                               const float* __restrict__ ln_b,
                                               float* __restrict__ out) {
  __shared__ float wf[NF_ * 32];   // [k][f][2]
  __shared__ float2 tw[512];
  const int tid = threadIdx.x;
  const int bh = blockIdx.x, bb = blockIdx.y;
  for (int j = tid; j < 512; j += 256) {
    float sv, cv; __sincosf((float)j * 0.01227184630f, &sv, &cv);
    tw[j] = make_float2(cv, sv);
  }
  for (int idx = tid; idx < NF_ * 16; idx += 256) {
    int k = idx >> 4, f = idx & 15;
    float2 fz = *(const float2*)(fftc + (bb * (NF_ * 16) + idx) * 2);
    float2 nz = *(const float2*)(nf + (bb * (NF_ * 16) + idx) * 2);
    float wv = wbuf[(bb * 16 + f) * NF_ + k];
    wf[k * 32 + f * 2] = fz.x + wv * (nz.x - fz.x);
    wf[k * 32 + f * 2 + 1] = fz.y + wv * (nz.y - fz.y);
  }
  __syncthreads();
  const int t = bh * 256 + tid;
  float acc[16];
#pragma unroll
  for (int f = 0; f < 16; ++f) acc[f] = 0.f;
  const float4* wf4 = (const float4*)wf;
  int id = 0;
  for (int k = 0; k < NF_; ++k) {
    float2 tv = tw[id];
    id = (id + t) & 511;
    float wgtk = (k == 0 || k == 256) ? 1.f : 2.f;  // Hermitian weight; sin=0 at DC/Nyq
    float c = tv.x * wgtk, s = tv.y * wgtk;
#pragma unroll
    for (int f2 = 0; f2 < 8; ++f2) {
      float4 v = wf4[k * 8 + f2];
      acc[2 * f2] += v.x * c - v.y * s;
      acc[2 * f2 + 1] += v.z * c - v.w * s;
    }
  }
  const float S = 0.04419417382f;
  float y[16];
  const float4* xp = (const float4*)(x + (bb * 512 + t) * 16);
  float mu = 0.f;
#pragma unroll
  for (int f2 = 0; f2 < 4; ++f2) {
    float4 xv = xp[f2];
    y[4 * f2 + 0] = fmaf(acc[4 * f2 + 0], S, xv.x);
    y[4 * f2 + 1] = fmaf(acc[4 * f2 + 1], S, xv.y);
    y[4 * f2 + 2] = fmaf(acc[4 * f2 + 2], S, xv.z);
    y[4 * f2 + 3] = fmaf(acc[4 * f2 + 3], S, xv.w);
  }
#pragma unroll
  for (int f = 0; f < 16; ++f) mu += y[f];
  mu *= 0.0625f;
  float var = 0.f;
#pragma unroll
  for (int f = 0; f < 16; ++f) { float dd = y[f] - mu; var += dd * dd; }
  var *= 0.0625f;
  float rs = rsqrtf(var + 1e-5f);
  float4* op = (float4*)(out + (bb * 512 + t) * 16);
#pragma unroll
  for (int f2 = 0; f2 < 4; ++f2) {
    op[f2] = make_float4(
        (y[4 * f2 + 0] - mu) * rs * ln_g[4 * f2 + 0] + ln_b[4 * f2 + 0],
        (y[4 * f2 + 1] - mu) * rs * ln_g[4 * f2 + 1] + ln_b[4 * f2 + 1],
        (y[4 * f2 + 2] - mu) * rs * ln_g[4 * f2 + 2] + ln_b[4 * f2 + 2],
        (y[4 * f2 + 3] - mu) * rs * ln_g[4 * f2 + 3] + ln_b[4 * f2 + 3]);
  }
}

extern "C" void kernel_launch(void* const* d_in, const int* in_sizes, int n_in,
                              void* d_out, int out_size, void* d_ws, size_t ws_size,
                              hipStream_t stream) {
  const float* x = (const float*)d_in[0];
  const float* W_proj = (const float*)d_in[1];
  const float* b_proj = (const float*)d_in[2];
  const float* W_gate = (const float*)d_in[3];
  const float* b_gate = (const float*)d_in[4];
  const float* mag_w = (const float*)d_in[5];
  const float* mag_b = (const float*)d_in[6];
  const float* phase_w = (const float*)d_in[7];
  const float* phase_b = (const float*)d_in[8];
  const float* ln_g = (const float*)d_in[9];
  const float* ln_b = (const float*)d_in[10];
  float* out = (float*)d_out;
  float* ws = (float*)d_ws;

  // workspace layout (floats): ~31.8 MB total
  float* csd = ws;                       //  65,792
  float* fftc = ws + 65792;              //  1,052,672
  float* nf = ws + 1118464;              //  1,052,672
  float* wbuf = ws + 2171136;            //  526,336
  float* gpart = ws + 2697472;           //  2,621,440
  unsigned short* wgt = (unsigned short*)(ws + 5318912);  // 320*16448 bf16

  hipLaunchKernelGGL(k_wgt, dim3(514, 10), dim3(256), 0, stream, W_gate, wgt);
  hipLaunchKernelGGL(k_csd, dim3(128), dim3(256), 0, stream, x, csd);
  hipLaunchKernelGGL(k_fft, dim3(2, 128), dim3(256), 0, stream, x, csd, fftc);
  hipLaunchKernelGGL(k_new, dim3(2056), dim3(256), 0, stream, fftc, W_proj, b_proj,
                     mag_w, mag_b, phase_w, phase_b, nf);
  hipLaunchKernelGGL(k_gemm, dim3(16, 5, 4), dim3(256), 0, stream, fftc, W_proj,
                     b_proj, wgt, gpart);
  hipLaunchKernelGGL(k_wred, dim3(2048), dim3(256), 0, stream, gpart, b_gate, wbuf);
  hipLaunchKernelGGL(k_recon, dim3(2, 128), dim3(256), 0, stream, fftc, nf, wbuf, x,
                     ln_g, ln_b, out);
}

// Round 3
// 307.596 us; speedup vs baseline: 1.2441x; 1.2441x over previous
//
#include <hip/hip_runtime.h>

// AdaptiveSpectrumLayer: B=128, H=T=512, F=16, HID=64, NF=257
// v2: rotation-recurrence DFTs (no twiddle gathers), k_gemm with N=320 in-block
// (A-recompute 1x), split-K=8, bf16 partials. ws stays 31.8 MB (proven cap).

#define NF_ 257
#define KDIM 16448   // NF_*64
#define NPAD 320
#define SPK 8

typedef __attribute__((ext_vector_type(8))) short short8;
typedef __attribute__((ext_vector_type(4))) float floatx4;

__device__ __forceinline__ unsigned int f2bf(float x) {
  union { float f; unsigned int u; } v; v.f = x;
  return (v.u + 0x7FFFu + ((v.u >> 16) & 1u)) >> 16;
}
__device__ __forceinline__ float bf2f(unsigned short u) {
  union { unsigned int u; float f; } v; v.u = ((unsigned int)u) << 16;
  return v.f;
}

// ---------- K0: W_gate (16448 x 257 f32) -> wgt bf16, transposed+padded (320 x 16448)
__global__ __launch_bounds__(256) void k_wgt(const float* __restrict__ Wg,
                                             unsigned short* __restrict__ wgt) {
  __shared__ float tile[32][33];
  const int tid = threadIdx.x;
  const int k0 = blockIdx.x * 32, n0 = blockIdx.y * 32;
  const int c = tid & 31, r = tid >> 5;
#pragma unroll
  for (int j = 0; j < 4; ++j) {
    int rr = r + j * 8;
    int n = n0 + c;
    tile[rr][c] = (n < NF_) ? Wg[(k0 + rr) * NF_ + n] : 0.f;
  }
  __syncthreads();
#pragma unroll
  for (int j = 0; j < 4; ++j) {
    int nn = r + j * 8;
    wgt[(n0 + nn) * KDIM + k0 + c] = (unsigned short)f2bf(tile[c][nn]);
  }
}

// ---------- K1: csd[b][k] = (1/(256*sqrt(512))) * DFT_t( autocorr(s)[t-255] )
// grid (2,128): bh = k-half, bb = batch. Rotation recurrence, no tw table.
__global__ __launch_bounds__(256) void k_csd(const float* __restrict__ x,
                                             float* __restrict__ csd) {
  __shared__ float sl[512];
  __shared__ float ol[512];
  const int tid = threadIdx.x, bh = blockIdx.x, bb = blockIdx.y;
  for (int t = tid; t < 512; t += 256) {
    const float4* xp = (const float4*)(x + (bb * 512 + t) * 16);
    float4 a = xp[0], c = xp[1], d = xp[2], e = xp[3];
    sl[t] = a.x + a.y + a.z + a.w + c.x + c.y + c.z + c.w +
            d.x + d.y + d.z + d.w + e.x + e.y + e.z + e.w;
  }
  __syncthreads();
  for (int t = tid; t < 512; t += 256) {
    int l = t - 255;
    int lo = l < 0 ? -l : 0;
    int hi = l > 0 ? 511 - l : 511;
    float a0 = 0.f, a1 = 0.f, a2 = 0.f, a3 = 0.f;
    int tau = lo;
    for (; tau + 3 <= hi; tau += 4) {
      a0 = fmaf(sl[tau], sl[tau + l], a0);
      a1 = fmaf(sl[tau + 1], sl[tau + 1 + l], a1);
      a2 = fmaf(sl[tau + 2], sl[tau + 2 + l], a2);
      a3 = fmaf(sl[tau + 3], sl[tau + 3 + l], a3);
    }
    float a = (a0 + a1) + (a2 + a3);
    for (; tau <= hi; ++tau) a = fmaf(sl[tau], sl[tau + l], a);
    ol[t] = a;
  }
  __syncthreads();
  const float S1 = 0.04419417382f / 256.f;
  const int kmax = (bh == 0) ? 129 : 128;
  if (tid < kmax) {
    const int k = bh * 129 + tid;
    float sth, cth;
    __sincosf((float)k * 0.01227184630f, &sth, &cth);  // 2*pi/512
    float c = 1.f, s = 0.f, re = 0.f, im = 0.f;
    for (int t = 0; t < 512; ++t) {
      float ov = ol[t];
      re = fmaf(ov, c, re);
      im = fmaf(-ov, s, im);
      float nc = fmaf(c, cth, -s * sth);
      s = fmaf(s, cth, c * sth);
      c = nc;
    }
    *(float2*)(csd + (bb * NF_ + k) * 2) = make_float2(re * S1, im * S1);
  }
}

// ---------- K2: fftc[b][k][f] = ortho-rfft(x)[k,f] + csd[b][k]
// grid (4,128): fq = f-quartet, bb = batch. thread = one k-bin, 4 f accumulators.
__global__ __launch_bounds__(256) void k_fft(const float* __restrict__ x,
                                             const float* __restrict__ csd,
                                             float* __restrict__ fftc) {
  __shared__ float xs[512 * 4];
  __shared__ float red[4][4];
  const int tid = threadIdx.x, fq = blockIdx.x, bb = blockIdx.y;
  for (int t = tid; t < 512; t += 256)
    *(float4*)&xs[t * 4] = *(const float4*)(x + (bb * 512 + t) * 16 + fq * 4);
  __syncthreads();
  const int k = tid;
  float sth, cth;
  __sincosf((float)k * 0.01227184630f, &sth, &cth);
  float c = 1.f, s = 0.f;
  float re0 = 0.f, re1 = 0.f, re2 = 0.f, re3 = 0.f;
  float im0 = 0.f, im1 = 0.f, im2 = 0.f, im3 = 0.f;
  for (int t = 0; t < 512; ++t) {
    float4 xv = *(const float4*)&xs[t * 4];   // broadcast (all lanes same addr)
    re0 = fmaf(xv.x, c, re0); im0 = fmaf(-xv.x, s, im0);
    re1 = fmaf(xv.y, c, re1); im1 = fmaf(-xv.y, s, im1);
    re2 = fmaf(xv.z, c, re2); im2 = fmaf(-xv.z, s, im2);
    re3 = fmaf(xv.w, c, re3); im3 = fmaf(-xv.w, s, im3);
    float nc = fmaf(c, cth, -s * sth);
    s = fmaf(s, cth, c * sth);
    c = nc;
  }
  const float S = 0.04419417382f;  // 1/sqrt(512)
  float2 cz = *(const float2*)(csd + (bb * NF_ + k) * 2);
  float* o = fftc + ((bb * NF_ + k) * 16 + fq * 4) * 2;
  o[0] = re0 * S + cz.x; o[1] = im0 * S + cz.y;
  o[2] = re1 * S + cz.x; o[3] = im1 * S + cz.y;
  o[4] = re2 * S + cz.x; o[5] = im2 * S + cz.y;
  o[6] = re3 * S + cz.x; o[7] = im3 * S + cz.y;
  // k = 256: re = sum_t (-1)^t x[t]; im = 0. Pair-diff + wave/block reduce.
  const int t0 = tid * 2;
  float p0 = xs[t0 * 4 + 0] - xs[t0 * 4 + 4];
  float p1 = xs[t0 * 4 + 1] - xs[t0 * 4 + 5];
  float p2 = xs[t0 * 4 + 2] - xs[t0 * 4 + 6];
  float p3 = xs[t0 * 4 + 3] - xs[t0 * 4 + 7];
#pragma unroll
  for (int off = 32; off; off >>= 1) {
    p0 += __shfl_down(p0, off);
    p1 += __shfl_down(p1, off);
    p2 += __shfl_down(p2, off);
    p3 += __shfl_down(p3, off);
  }
  if ((tid & 63) == 0) {
    red[tid >> 6][0] = p0; red[tid >> 6][1] = p1;
    red[tid >> 6][2] = p2; red[tid >> 6][3] = p3;
  }
  __syncthreads();
  if (tid == 0) {
    float2 cz2 = *(const float2*)(csd + (bb * NF_ + 256) * 2);
#pragma unroll
    for (int j = 0; j < 4; ++j) {
      float r = red[0][j] + red[1][j] + red[2][j] + red[3][j];
      float* oo = fftc + ((bb * NF_ + 256) * 16 + fq * 4 + j) * 2;
      oo[0] = r * S + cz2.x;
      oo[1] = cz2.y;
    }
  }
}

// ---------- K3: new_fft[b][n][f] from recomputed proj + per-freq complexifier
__global__ __launch_bounds__(256) void k_new(const float* __restrict__ fftc,
                                             const float* __restrict__ W_proj,
                                             const float* __restrict__ b_proj,
                                             const float* __restrict__ mag_w,
                                             const float* __restrict__ mag_b,
                                             const float* __restrict__ phase_w,
                                             const float* __restrict__ phase_b,
                                             float* __restrict__ nf) {
  __shared__ float wp[256], bp[64];
  const int tid = threadIdx.x;
  wp[tid] = W_proj[tid];
  if (tid < 64) bp[tid] = b_proj[tid];
  __syncthreads();
  const int idx = blockIdx.x * 256 + tid;  // < 128*257*16
  const int bn = idx >> 4;
  const int n = bn % NF_;
  float2 z = *(const float2*)(fftc + idx * 2);
  float d = z.x * z.x + z.y * z.y;
  float ir = d > 0.f ? rsqrtf(d) : 0.f;
  float mag = d * ir;
  float sn = z.y * ir;
  float cs = d > 0.f ? z.x * ir : 1.f;
  float fr = (float)n * 0.1953125f;  // 100/512
  float am = 0.f, ap = 0.f;
#pragma unroll 8
  for (int h = 0; h < 64; ++h) {
    float p = fmaf(mag, wp[h], fmaf(sn, wp[64 + h], fmaf(cs, wp[128 + h],
              fmaf(fr, wp[192 + h], bp[h]))));
    p = fmaxf(p, 0.f);
    am = fmaf(p, mag_w[n * 64 + h], am);
    ap = fmaf(p, phase_w[n * 64 + h], ap);
  }
  float m = fmaxf(am + mag_b[n], 0.f);
  float ph = 6.28318530718f / (1.f + __expf(-(ap + phase_b[n])));
  float sp, cp;
  __sincosf(ph, &sp, &cp);
  *(float2*)(nf + idx * 2) = make_float2(m * cp, m * sp);
}

// ---------- K4: gate GEMM partials. C(2048 x 320) = A(2048 x 16448) * B.
// Block: M=64, N=320 (full), 256 threads / 4 waves (each 4m x 5n tiles).
// A = proj recomputed from fftc (1x, in-block). split-K = 8 -> 256 blocks.
__global__ __launch_bounds__(256, 2) void k_gemm(const float* __restrict__ fftc,
                                                 const float* __restrict__ W_proj,
                                                 const float* __restrict__ b_proj,
                                                 const unsigned short* __restrict__ wgt,
                                                 unsigned short* __restrict__ gpart) {
  __shared__ __align__(16) unsigned short As[64 * 72];
  __shared__ __align__(16) unsigned short Bs[320 * 72];
  const int tid = threadIdx.x;
  const int mt = blockIdx.x, sp = blockIdx.y;
  const int i0 = (NF_ * sp) / SPK, i1 = (NF_ * (sp + 1)) / SPK;

  // A staging role: rows {rp, rp+32}, h-chunk hg*8..+8
  const int rp = tid >> 3, hg = tid & 7;
  float w0[8], w1[8], w2[8], w3[8], bpv[8];
#pragma unroll
  for (int j = 0; j < 8; ++j) {
    int h = hg * 8 + j;
    w0[j] = W_proj[h];       w1[j] = W_proj[64 + h];
    w2[j] = W_proj[128 + h]; w3[j] = W_proj[192 + h];
    bpv[j] = b_proj[h];
  }
  const int gm1 = mt * 64 + rp, gm2 = gm1 + 32;
  const int bb1 = gm1 >> 4, ff1 = gm1 & 15;
  const int bb2 = gm2 >> 4, ff2 = gm2 & 15;
  // B staging role: n rows {nb + 32q}, k-chunk part*8..+8
  const int nb = tid >> 3, part = tid & 7;
  const unsigned short* bbase = wgt + nb * KDIM + part * 8;

  const int lane = tid & 63, wn = tid >> 6;
  const int l15 = lane & 15, quad = lane >> 4;

  floatx4 acc[4][5];
#pragma unroll
  for (int a = 0; a < 4; ++a)
#pragma unroll
    for (int b = 0; b < 5; ++b) acc[a][b] = (floatx4){0.f, 0.f, 0.f, 0.f};

  // prefetch i0
  uint4 bv[10];
#pragma unroll
  for (int q = 0; q < 10; ++q)
    bv[q] = *(const uint4*)(bbase + q * (32 * KDIM) + i0 * 64);
  float2 z1 = *(const float2*)(fftc + ((bb1 * NF_ + i0) * 16 + ff1) * 2);
  float2 z2 = *(const float2*)(fftc + ((bb2 * NF_ + i0) * 16 + ff2) * 2);

  for (int i = i0; i < i1; ++i) {
    // features for current i
    float fr = (float)i * 0.1953125f;
    float d1 = z1.x * z1.x + z1.y * z1.y;
    float ir1 = d1 > 0.f ? rsqrtf(d1) : 0.f;
    float mag1 = d1 * ir1, sn1 = z1.y * ir1, cs1 = d1 > 0.f ? z1.x * ir1 : 1.f;
    float d2 = z2.x * z2.x + z2.y * z2.y;
    float ir2 = d2 > 0.f ? rsqrtf(d2) : 0.f;
    float mag2 = d2 * ir2, sn2 = z2.y * ir2, cs2 = d2 > 0.f ? z2.x * ir2 : 1.f;
    unsigned int pk1[4], pk2[4];
#pragma unroll
    for (int jj = 0; jj < 4; ++jj) {
      float p0 = fmaf(mag1, w0[2 * jj], fmaf(sn1, w1[2 * jj],
                 fmaf(cs1, w2[2 * jj], fmaf(fr, w3[2 * jj], bpv[2 * jj]))));
      float p1 = fmaf(mag1, w0[2 * jj + 1], fmaf(sn1, w1[2 * jj + 1],
                 fmaf(cs1, w2[2 * jj + 1], fmaf(fr, w3[2 * jj + 1], bpv[2 * jj + 1]))));
      float q0 = fmaf(mag2, w0[2 * jj], fmaf(sn2, w1[2 * jj],
                 fmaf(cs2, w2[2 * jj], fmaf(fr, w3[2 * jj], bpv[2 * jj]))));
      float q1 = fmaf(mag2, w0[2 * jj + 1], fmaf(sn2, w1[2 * jj + 1],
                 fmaf(cs2, w2[2 * jj + 1], fmaf(fr, w3[2 * jj + 1], bpv[2 * jj + 1]))));
      p0 = fmaxf(p0, 0.f); p1 = fmaxf(p1, 0.f);
      q0 = fmaxf(q0, 0.f); q1 = fmaxf(q1, 0.f);
      pk1[jj] = f2bf(p0) | (f2bf(p1) << 16);
      pk2[jj] = f2bf(q0) | (f2bf(q1) << 16);
    }
    __syncthreads();  // previous iteration's fragment reads complete
    *(uint4*)&As[rp * 72 + hg * 8] = make_uint4(pk1[0], pk1[1], pk1[2], pk1[3]);
    *(uint4*)&As[(rp + 32) * 72 + hg * 8] = make_uint4(pk2[0], pk2[1], pk2[2], pk2[3]);
#pragma unroll
    for (int q = 0; q < 10; ++q)
      *(uint4*)&Bs[(nb + 32 * q) * 72 + part * 8] = bv[q];
    // prefetch next i (lands during MFMA phase)
    if (i + 1 < i1) {
      const int ix = i + 1;
#pragma unroll
      for (int q = 0; q < 10; ++q)
        bv[q] = *(const uint4*)(bbase + q * (32 * KDIM) + ix * 64);
      z1 = *(const float2*)(fftc + ((bb1 * NF_ + ix) * 16 + ff1) * 2);
      z2 = *(const float2*)(fftc + ((bb2 * NF_ + ix) * 16 + ff2) * 2);
    }
    __syncthreads();
#pragma unroll
    for (int kh = 0; kh < 64; kh += 32) {
      short8 af[4];
#pragma unroll
      for (int mi = 0; mi < 4; ++mi)
        af[mi] = *(const short8*)&As[(mi * 16 + l15) * 72 + kh + quad * 8];
#pragma unroll
      for (int ni = 0; ni < 5; ++ni) {
        short8 bfv = *(const short8*)&Bs[(wn * 80 + ni * 16 + l15) * 72 + kh + quad * 8];
#pragma unroll
        for (int mi = 0; mi < 4; ++mi)
          acc[mi][ni] = __builtin_amdgcn_mfma_f32_16x16x32_bf16(af[mi], bfv,
                                                                acc[mi][ni], 0, 0, 0);
      }
    }
  }
  unsigned short* gp = gpart + sp * (2048 * NPAD);
#pragma unroll
  for (int mi = 0; mi < 4; ++mi)
#pragma unroll
    for (int ni = 0; ni < 5; ++ni)
#pragma unroll
      for (int r = 0; r < 4; ++r) {
        int row = mt * 64 + mi * 16 + quad * 4 + r;
        int col = wn * 80 + ni * 16 + l15;
        gp[row * NPAD + col] = (unsigned short)f2bf(acc[mi][ni][r]);
      }
}

// ---------- K4r: sum split-K bf16 partials + bias -> SiLU -> sigmoid -> w
__global__ __launch_bounds__(256) void k_wred(const unsigned short* __restrict__ gpart,
                                              const float* __restrict__ b_gate,
                                              float* __restrict__ wbuf) {
  const int m = blockIdx.x;
  for (int n = threadIdx.x; n < NF_; n += 256) {
    float g = b_gate[n];
#pragma unroll
    for (int s2 = 0; s2 < SPK; ++s2)
      g += bf2f(gpart[s2 * (2048 * NPAD) + m * NPAD + n]);
    float sg = 1.f / (1.f + __expf(-g));
    float gs = g * sg;
    wbuf[m * NF_ + n] = 1.f / (1.f + __expf(-gs));
  }
}

// ---------- K5: blend + ortho-irfft (rotation recurrence) + residual + LayerNorm
// grid (4,128): bh = t-quarter (128 t), bb = batch. 256 thr = 128 t x 2 f-halves.
__global__ __launch_bounds__(256) void k_recon(const float* __restrict__ fftc,
                                               const float* __restrict__ nf,
                                               const float* __restrict__ wbuf,
                                               const float* __restrict__ x,
                                               const float* __restrict__ ln_g,
                                               const float* __restrict__ ln_b,
                                               float* __restrict__ out) {
  __shared__ float wfs[NF_ * 32];  // [k][f][2], Hermitian x2 folded in
  __shared__ float ls1[256], ls2[256];
  const int tid = threadIdx.x, bh = blockIdx.x, bb = blockIdx.y;
  for (int idx = tid; idx < NF_ * 16; idx += 256) {
    int k = idx >> 4, f = idx & 15;
    float2 fz = *(const float2*)(fftc + (bb * (NF_ * 16) + idx) * 2);
    float2 nz = *(const float2*)(nf + (bb * (NF_ * 16) + idx) * 2);
    float wv = wbuf[(bb * 16 + f) * NF_ + k];
    float sc = (k == 0 || k == 256) ? 1.f : 2.f;
    wfs[k * 32 + f * 2] = sc * (fz.x + wv * (nz.x - fz.x));
    wfs[k * 32 + f * 2 + 1] = sc * (fz.y + wv * (nz.y - fz.y));
  }
  __syncthreads();
  const int t = bh * 128 + (tid & 127), fh = tid >> 7;
  float sth, cth;
  __sincosf((float)t * 0.01227184630f, &sth, &cth);
  float c = 1.f, s = 0.f;
  float acc[8];
#pragma unroll
  for (int j = 0; j < 8; ++j) acc[j] = 0.f;
  const float4* wp4 = (const float4*)wfs;
  for (int k = 0; k < NF_; ++k) {
    float4 v0 = wp4[k * 8 + fh * 4 + 0];   // broadcast reads (k uniform per wave)
    float4 v1 = wp4[k * 8 + fh * 4 + 1];
    float4 v2 = wp4[k * 8 + fh * 4 + 2];
    float4 v3 = wp4[k * 8 + fh * 4 + 3];
    acc[0] = fmaf(v0.x, c, acc[0]); acc[0] = fmaf(-v0.y, s, acc[0]);
    acc[1] = fmaf(v0.z, c, acc[1]); acc[1] = fmaf(-v0.w, s, acc[1]);
    acc[2] = fmaf(v1.x, c, acc[2]); acc[2] = fmaf(-v1.y, s, acc[2]);
    acc[3] = fmaf(v1.z, c, acc[3]); acc[3] = fmaf(-v1.w, s, acc[3]);
    acc[4] = fmaf(v2.x, c, acc[4]); acc[4] = fmaf(-v2.y, s, acc[4]);
    acc[5] = fmaf(v2.z, c, acc[5]); acc[5] = fmaf(-v2.w, s, acc[5]);
    acc[6] = fmaf(v3.x, c, acc[6]); acc[6] = fmaf(-v3.y, s, acc[6]);
    acc[7] = fmaf(v3.z, c, acc[7]); acc[7] = fmaf(-v3.w, s, acc[7]);
    float nc = fmaf(c, cth, -s * sth);
    s = fmaf(s, cth, c * sth);
    c = nc;
  }
  const float S = 0.04419417382f;
  const float* xr = x + (bb * 512 + t) * 16 + fh * 8;
  float4 xa = *(const float4*)xr, xb = *(const float4*)(xr + 4);
  float y[8];
  y[0] = fmaf(acc[0], S, xa.x); y[1] = fmaf(acc[1], S, xa.y);
  y[2] = fmaf(acc[2], S, xa.z); y[3] = fmaf(acc[3], S, xa.w);
  y[4] = fmaf(acc[4], S, xb.x); y[5] = fmaf(acc[5], S, xb.y);
  y[6] = fmaf(acc[6], S, xb.z); y[7] = fmaf(acc[7], S, xb.w);
  float s1 = 0.f, s2 = 0.f;
#pragma unroll
  for (int j = 0; j < 8; ++j) { s1 += y[j]; s2 = fmaf(y[j], y[j], s2); }
  ls1[tid] = s1; ls2[tid] = s2;
  __syncthreads();
  const int o = tid ^ 128;
  float t1 = s1 + ls1[o], t2 = s2 + ls2[o];
  float mu = t1 * 0.0625f;
  float var = t2 * 0.0625f - mu * mu;
  float rs = rsqrtf(var + 1e-5f);
  float* orow = out + (bb * 512 + t) * 16 + fh * 8;
  float4 o0, o1;
  o0.x = (y[0] - mu) * rs * ln_g[fh * 8 + 0] + ln_b[fh * 8 + 0];
  o0.y = (y[1] - mu) * rs * ln_g[fh * 8 + 1] + ln_b[fh * 8 + 1];
  o0.z = (y[2] - mu) * rs * ln_g[fh * 8 + 2] + ln_b[fh * 8 + 2];
  o0.w = (y[3] - mu) * rs * ln_g[fh * 8 + 3] + ln_b[fh * 8 + 3];
  o1.x = (y[4] - mu) * rs * ln_g[fh * 8 + 4] + ln_b[fh * 8 + 4];
  o1.y = (y[5] - mu) * rs * ln_g[fh * 8 + 5] + ln_b[fh * 8 + 5];
  o1.z = (y[6] - mu) * rs * ln_g[fh * 8 + 6] + ln_b[fh * 8 + 6];
  o1.w = (y[7] - mu) * rs * ln_g[fh * 8 + 7] + ln_b[fh * 8 + 7];
  *(float4*)orow = o0;
  *(float4*)(orow + 4) = o1;
}

extern "C" void kernel_launch(void* const* d_in, const int* in_sizes, int n_in,
                              void* d_out, int out_size, void* d_ws, size_t ws_size,
                              hipStream_t stream) {
  const float* x = (const float*)d_in[0];
  const float* W_proj = (const float*)d_in[1];
  const float* b_proj = (const float*)d_in[2];
  const float* W_gate = (const float*)d_in[3];
  const float* b_gate = (const float*)d_in[4];
  const float* mag_w = (const float*)d_in[5];
  const float* mag_b = (const float*)d_in[6];
  const float* phase_w = (const float*)d_in[7];
  const float* phase_b = (const float*)d_in[8];
  const float* ln_g = (const float*)d_in[9];
  const float* ln_b = (const float*)d_in[10];
  float* out = (float*)d_out;
  float* ws = (float*)d_ws;

  // workspace layout (float slots): 7,950,592 = 31.8 MB (same as proven v1)
  float* csd = ws;                                        //    65,792
  float* fftc = ws + 65792;                               // 1,052,672
  float* nf = ws + 1118464;                               // 1,052,672
  float* wbuf = ws + 2171136;                             //   526,336
  unsigned short* gpart = (unsigned short*)(ws + 2697472);// SPK*2048*320 bf16
  unsigned short* wgt = (unsigned short*)(ws + 5318912);  // 320*16448 bf16

  hipLaunchKernelGGL(k_wgt, dim3(514, 10), dim3(256), 0, stream, W_gate, wgt);
  hipLaunchKernelGGL(k_csd, dim3(2, 128), dim3(256), 0, stream, x, csd);
  hipLaunchKernelGGL(k_fft, dim3(4, 128), dim3(256), 0, stream, x, csd, fftc);
  hipLaunchKernelGGL(k_new, dim3(2056), dim3(256), 0, stream, fftc, W_proj, b_proj,
                     mag_w, mag_b, phase_w, phase_b, nf);
  hipLaunchKernelGGL(k_gemm, dim3(32, SPK), dim3(256), 0, stream, fftc, W_proj,
                     b_proj, wgt, gpart);
  hipLaunchKernelGGL(k_wred, dim3(2048), dim3(256), 0, stream, gpart, b_gate, wbuf);
  hipLaunchKernelGGL(k_recon, dim3(4, 128), dim3(256), 0, stream, fftc, nf, wbuf, x,
                     ln_g, ln_b, out);
}